// Round 2
// baseline (3234.812 us; speedup 1.0000x reference)
//
#include <hip/hip_runtime.h>

#define BM 128
#define BK 64
#define BD 16
#define NT 256

// ---------------- centroid norms ----------------
__global__ void cnorm_kernel(const float* __restrict__ C, float* __restrict__ cnorm,
                             int D, int K) {
  int k = blockIdx.x * blockDim.x + threadIdx.x;
  if (k >= K) return;
  float s = 0.f;
  for (int d = 0; d < D; ++d) {
    float v = C[(size_t)d * K + k];   // coalesced across threads
    s = fmaf(v, v, s);
  }
  cnorm[k] = s;
}

// ---------------- init best keys ----------------
__global__ void init_kernel(unsigned long long* best, int N) {
  int n = blockIdx.x * blockDim.x + threadIdx.x;
  if (n < N) best[n] = ~0ULL;
}

__device__ __forceinline__ unsigned int fsortable(float f) {
  unsigned int u = __float_as_uint(f);
  return (u & 0x80000000u) ? ~u : (u | 0x80000000u);  // monotonic float->uint
}

// ---------------- fused GEMM + argmin ----------------
__global__ __launch_bounds__(NT) void assign_kernel(
    const float* __restrict__ X, const float* __restrict__ C,
    const float* __restrict__ cnorm, unsigned long long* __restrict__ best,
    int N, int D, int K) {
  __shared__ float Xs[BD][BM];   // d-major so fragment reads are float4
  __shared__ float Cs[BD][BK];

  const int t  = threadIdx.x;
  const int tx = t & 15;         // 16 col-groups * 4 cols
  const int ty = t >> 4;         // 16 row-groups * 8 rows
  const int k0 = blockIdx.x * BK;
  const int n0 = blockIdx.y * BM;

  float acc[8][4];
#pragma unroll
  for (int i = 0; i < 8; ++i)
#pragma unroll
    for (int j = 0; j < 4; ++j) acc[i][j] = 0.f;

  for (int d0 = 0; d0 < D; d0 += BD) {
    // stage X tile: 128 rows x 16 d  (512 float4 loads, transposed store)
#pragma unroll
    for (int v = 0; v < 2; ++v) {
      int f4  = t + v * 256;          // 0..511
      int row = f4 >> 2;              // 0..127
      int dc  = (f4 & 3) * 4;
      const float4 xv = *(const float4*)&X[(size_t)(n0 + row) * D + d0 + dc];
      Xs[dc + 0][row] = xv.x;
      Xs[dc + 1][row] = xv.y;
      Xs[dc + 2][row] = xv.z;
      Xs[dc + 3][row] = xv.w;
    }
    // stage C tile: 16 d x 64 cols (256 float4 loads, contiguous)
    {
      int d  = t >> 4;
      int kc = (t & 15) * 4;
      int k  = k0 + kc;
      float4 cv;
      if (k + 3 < K) {
        cv = *(const float4*)&C[(size_t)(d0 + d) * K + k];
      } else {
        cv.x = (k + 0 < K) ? C[(size_t)(d0 + d) * K + k + 0] : 0.f;
        cv.y = (k + 1 < K) ? C[(size_t)(d0 + d) * K + k + 1] : 0.f;
        cv.z = (k + 2 < K) ? C[(size_t)(d0 + d) * K + k + 2] : 0.f;
        cv.w = (k + 3 < K) ? C[(size_t)(d0 + d) * K + k + 3] : 0.f;
      }
      *(float4*)&Cs[d][kc] = cv;
    }
    __syncthreads();

#pragma unroll
    for (int d = 0; d < BD; ++d) {
      float4 a0 = *(const float4*)&Xs[d][ty * 8];
      float4 a1 = *(const float4*)&Xs[d][ty * 8 + 4];
      float4 b  = *(const float4*)&Cs[d][tx * 4];
      float av[8] = {a0.x, a0.y, a0.z, a0.w, a1.x, a1.y, a1.z, a1.w};
      float bv[4] = {b.x, b.y, b.z, b.w};
#pragma unroll
      for (int i = 0; i < 8; ++i)
#pragma unroll
        for (int j = 0; j < 4; ++j) acc[i][j] = fmaf(av[i], bv[j], acc[i][j]);
    }
    __syncthreads();
  }

  // score = cnorm[k] - 2*dot  (x_norm is row-constant, irrelevant to argmin)
  float cn[4];
#pragma unroll
  for (int j = 0; j < 4; ++j) {
    int k = k0 + tx * 4 + j;
    cn[j] = (k < K) ? cnorm[k] : 0.f;
  }

#pragma unroll
  for (int i = 0; i < 8; ++i) {
    unsigned long long key = ~0ULL;
#pragma unroll
    for (int j = 0; j < 4; ++j) {
      int k = k0 + tx * 4 + j;
      if (k < K) {
        float score = fmaf(-2.f, acc[i][j], cn[j]);
        unsigned long long cand =
            ((unsigned long long)fsortable(score) << 32) | (unsigned)k;
        key = key < cand ? key : cand;
      }
    }
    // min-reduce across the 16 tx lanes (contiguous within a wave)
#pragma unroll
    for (int m = 8; m >= 1; m >>= 1) {
      unsigned long long other = __shfl_xor(key, m, 16);
      key = key < other ? key : other;
    }
    if (tx == 0) atomicMin(&best[n0 + ty * 8 + i], key);
  }
}

// ---------------- unpack to output (int32 indices!) ----------------
__global__ void out_kernel(const unsigned long long* __restrict__ best,
                           int* __restrict__ out, int N) {
  int n = blockIdx.x * blockDim.x + threadIdx.x;
  if (n < N) out[n] = (int)(unsigned int)(best[n] & 0xffffffffu);
}

extern "C" void kernel_launch(void* const* d_in, const int* in_sizes, int n_in,
                              void* d_out, int out_size, void* d_ws, size_t ws_size,
                              hipStream_t stream) {
  const float* X = (const float*)d_in[0];     // [N, D]
  const float* C = (const float*)d_in[1];     // [D, K]
  const int N = 16384, D = 768, K = 10000;

  unsigned long long* best = (unsigned long long*)d_ws;               // 128 KiB
  float* cnorm = (float*)((char*)d_ws + (size_t)N * sizeof(unsigned long long));
  int* out = (int*)d_out;

  hipLaunchKernelGGL(init_kernel, dim3((N + 255) / 256), dim3(256), 0, stream,
                     best, N);
  hipLaunchKernelGGL(cnorm_kernel, dim3((K + 255) / 256), dim3(256), 0, stream,
                     C, cnorm, D, K);
  dim3 grid((K + BK - 1) / BK, N / BM);
  hipLaunchKernelGGL(assign_kernel, grid, dim3(NT), 0, stream, X, C, cnorm,
                     best, N, D, K);
  hipLaunchKernelGGL(out_kernel, dim3((N + 255) / 256), dim3(256), 0, stream,
                     best, out, N);
}

// Round 3
// 904.060 us; speedup vs baseline: 3.5781x; 3.5781x over previous
//
#include <hip/hip_runtime.h>
#include <cfloat>

#define N_ROWS 16384
#define DDIM   768
#define KCOLS  10000
#define KPAD   10112   // 79 * 128

typedef __attribute__((ext_vector_type(4))) float f32x4;
typedef __attribute__((ext_vector_type(8))) short s16x8;
typedef unsigned long long u64;
typedef unsigned int u32;

__device__ __forceinline__ u32 fsort(float f) {
  u32 u = __float_as_uint(f);
  return (u & 0x80000000u) ? ~u : (u | 0x80000000u);
}
__device__ __forceinline__ float funsort(u32 u) {
  u32 b = (u & 0x80000000u) ? (u ^ 0x80000000u) : ~u;
  return __uint_as_float(b);
}
__device__ __forceinline__ unsigned short f2bf(float f) {  // RNE
  u32 b = __float_as_uint(f);
  return (unsigned short)((b + 0x7fffu + ((b >> 16) & 1u)) >> 16);
}

// ============================ MFMA fast path ============================

__global__ void init2_kernel(u64* best, u32* amin) {
  int i = blockIdx.x * 256 + threadIdx.x;
  if (i < N_ROWS) { best[i] = ~0ULL; amin[i] = 0xFFFFFFFFu; }
}

__global__ void convx_kernel(const float* __restrict__ X, unsigned short* __restrict__ Xb) {
  int i = blockIdx.x * 256 + threadIdx.x;        // one thread = 8 elements
  const float4* p = (const float4*)X + (size_t)i * 2;
  float4 a = p[0], b = p[1];
  union { unsigned short s[8]; uint4 v; } o;
  o.s[0] = f2bf(a.x); o.s[1] = f2bf(a.y); o.s[2] = f2bf(a.z); o.s[3] = f2bf(a.w);
  o.s[4] = f2bf(b.x); o.s[5] = f2bf(b.y); o.s[6] = f2bf(b.z); o.s[7] = f2bf(b.w);
  *((uint4*)Xb + i) = o.v;
}

// C [768][10000] f32  ->  Cb [10112][768] bf16 (zero-padded rows)
__global__ void transc_kernel(const float* __restrict__ C, unsigned short* __restrict__ Cb) {
  __shared__ float tile[32][33];
  int t = threadIdx.x, tx = t & 31, ty = t >> 5;
  int kk = blockIdx.x * 32, dd = blockIdx.y * 32;
#pragma unroll
  for (int j = 0; j < 4; ++j) {
    int d = dd + ty + j * 8, k = kk + tx;
    tile[ty + j * 8][tx] = (k < KCOLS) ? C[(size_t)d * KCOLS + k] : 0.f;
  }
  __syncthreads();
#pragma unroll
  for (int j = 0; j < 4; ++j) {
    int k = kk + ty + j * 8, d = dd + tx;
    Cb[(size_t)k * DDIM + d] = f2bf(tile[tx][ty + j * 8]);
  }
}

__global__ void cnormp_kernel(const float* __restrict__ C, float* __restrict__ cn) {
  int k = blockIdx.x * 256 + threadIdx.x;
  if (k >= KPAD) return;
  if (k >= KCOLS) { cn[k] = FLT_MAX; return; }
  float s = 0.f;
  for (int d = 0; d < DDIM; ++d) {
    float v = C[(size_t)d * KCOLS + k];
    s = fmaf(v, v, s);
  }
  cn[k] = s;
}

#define GLOAD_LDS16(gp, lp)                                                     \
  __builtin_amdgcn_global_load_lds((const __attribute__((address_space(1))) void*)(gp), \
                                   (__attribute__((address_space(3))) void*)(lp), 16, 0, 0)

__global__ __launch_bounds__(256) void assign_mfma(
    const unsigned short* __restrict__ Xb, const unsigned short* __restrict__ Cb,
    const float* __restrict__ X32, const float* __restrict__ C32,
    const float* __restrict__ cn, u32* __restrict__ amin, u64* __restrict__ best) {
  __shared__ unsigned short As[128 * 64];   // [row][d], 64 bf16 per row
  __shared__ unsigned short Bs[128 * 64];   // [kcol][d]

  const int t = threadIdx.x;
  const int lane = t & 63, wave = t >> 6;
  const int wr = wave >> 1, wc = wave & 1;
  const int n0 = blockIdx.x * 128;          // row block
  const int k0 = blockIdx.y * 128;          // col block
  const int lr = lane & 15, lg = lane >> 4;
  const int srow = lane >> 3, schunk = lane & 7;

  f32x4 acc[4][4];
  f32x4 z = {0.f, 0.f, 0.f, 0.f};
#pragma unroll
  for (int m = 0; m < 4; ++m)
#pragma unroll
    for (int n = 0; n < 4; ++n) acc[m][n] = z;

  const unsigned short* gA[4];
  const unsigned short* gB[4];
  unsigned short* lA[4];
  unsigned short* lB[4];
#pragma unroll
  for (int i = 0; i < 4; ++i) {
    int r = wave * 32 + i * 8 + srow;
    gA[i] = Xb + (size_t)(n0 + r) * DDIM + schunk * 8;
    gB[i] = Cb + (size_t)(k0 + r) * DDIM + schunk * 8;
    lA[i] = As + (wave * 32 + i * 8) * 64;
    lB[i] = Bs + (wave * 32 + i * 8) * 64;
  }

  for (int d0 = 0; d0 < DDIM; d0 += 64) {
#pragma unroll
    for (int i = 0; i < 4; ++i) GLOAD_LDS16(gA[i] + d0, lA[i]);
#pragma unroll
    for (int i = 0; i < 4; ++i) GLOAD_LDS16(gB[i] + d0, lB[i]);
    __syncthreads();
#pragma unroll
    for (int dk = 0; dk < 2; ++dk) {
      const int doff = dk * 32 + lg * 8;
      s16x8 af[4], bfr[4];
#pragma unroll
      for (int m = 0; m < 4; ++m)
        af[m] = *(const s16x8*)(As + (wr * 64 + m * 16 + lr) * 64 + doff);
#pragma unroll
      for (int n = 0; n < 4; ++n)
        bfr[n] = *(const s16x8*)(Bs + (wc * 64 + n * 16 + lr) * 64 + doff);
#pragma unroll
      for (int m = 0; m < 4; ++m)
#pragma unroll
        for (int n = 0; n < 4; ++n)
          acc[m][n] = __builtin_amdgcn_mfma_f32_16x16x32_bf16(af[m], bfr[n], acc[m][n], 0, 0, 0);
    }
    __syncthreads();
  }

  // ---------------- epilogue: approx min + exact rescore ----------------
  float cnv[4];
#pragma unroll
  for (int n = 0; n < 4; ++n) cnv[n] = cn[k0 + wc * 64 + n * 16 + lr];

#pragma unroll
  for (int m = 0; m < 4; ++m) {
    float sc[4][4];  // [n][e]
#pragma unroll
    for (int n = 0; n < 4; ++n)
#pragma unroll
      for (int e = 0; e < 4; ++e) sc[n][e] = fmaf(-2.f, acc[m][n][e], cnv[n]);

    float th[4];
#pragma unroll
    for (int e = 0; e < 4; ++e) {
      float v = fminf(fminf(sc[0][e], sc[1][e]), fminf(sc[2][e], sc[3][e]));
      u32 key = fsort(v);
#pragma unroll
      for (int s = 1; s < 16; s <<= 1) {
        u32 o = __shfl_xor(key, s);
        key = key < o ? key : o;
      }
      int row = n0 + wr * 64 + m * 16 + lg * 4 + e;
      u32 mr = key;
      if (lr == 0) {
        u32 old = atomicMin(&amin[row], key);
        mr = old < key ? old : key;
      }
      mr = __shfl(mr, lane & 48);       // broadcast from lr==0 lane of group
      th[e] = funsort(mr) + 1.5f;       // MARGIN (bf16 err sigma ~0.089; 8.4 sigma)
    }

#pragma unroll
    for (int n = 0; n < 4; ++n) {
#pragma unroll
      for (int e = 0; e < 4; ++e) {
        int kq = k0 + wc * 64 + n * 16 + lr;
        bool cand = (kq < KCOLS) && (sc[n][e] <= th[e]);
        u64 mask = __ballot(cand);
        while (mask) {
          int src = (int)__builtin_ctzll(mask);
          mask &= mask - 1;
          int srowg = n0 + wr * 64 + m * 16 + ((src >> 4) & 3) * 4 + e;
          int skg = k0 + wc * 64 + n * 16 + (src & 15);
          // exact fp32 dot, 64-lane parallel
          float part = 0.f;
          const float* xp = X32 + (size_t)srowg * DDIM + lane;
          const float* cp = C32 + (size_t)lane * KCOLS + skg;
#pragma unroll
          for (int i = 0; i < 12; ++i)
            part = fmaf(xp[i * 64], cp[(size_t)i * 64 * KCOLS], part);
#pragma unroll
          for (int s = 1; s < 64; s <<= 1) part += __shfl_xor(part, s);
          if (lane == 0) {
            float ex = fmaf(-2.f, part, cn[skg]);
            atomicMin(&best[srowg], ((u64)fsort(ex) << 32) | (u32)skg);
          }
        }
      }
    }
  }
}

// ============================ fp32 fallback path ============================

__global__ void cnorm_kernel(const float* __restrict__ C, float* __restrict__ cnorm,
                             int D, int K) {
  int k = blockIdx.x * blockDim.x + threadIdx.x;
  if (k >= K) return;
  float s = 0.f;
  for (int d = 0; d < D; ++d) {
    float v = C[(size_t)d * K + k];
    s = fmaf(v, v, s);
  }
  cnorm[k] = s;
}

__global__ void init_kernel(u64* best, int N) {
  int n = blockIdx.x * blockDim.x + threadIdx.x;
  if (n < N) best[n] = ~0ULL;
}

__global__ __launch_bounds__(256) void assign_kernel(
    const float* __restrict__ X, const float* __restrict__ C,
    const float* __restrict__ cnorm, u64* __restrict__ best,
    int N, int D, int K) {
  __shared__ float Xs[16][128];
  __shared__ float Cs[16][64];
  const int t = threadIdx.x;
  const int tx = t & 15, ty = t >> 4;
  const int k0 = blockIdx.x * 64;
  const int n0 = blockIdx.y * 128;
  float acc[8][4];
#pragma unroll
  for (int i = 0; i < 8; ++i)
#pragma unroll
    for (int j = 0; j < 4; ++j) acc[i][j] = 0.f;
  for (int d0 = 0; d0 < D; d0 += 16) {
#pragma unroll
    for (int v = 0; v < 2; ++v) {
      int f4 = t + v * 256;
      int row = f4 >> 2;
      int dc = (f4 & 3) * 4;
      const float4 xv = *(const float4*)&X[(size_t)(n0 + row) * D + d0 + dc];
      Xs[dc + 0][row] = xv.x; Xs[dc + 1][row] = xv.y;
      Xs[dc + 2][row] = xv.z; Xs[dc + 3][row] = xv.w;
    }
    {
      int d = t >> 4, kc = (t & 15) * 4, k = k0 + kc;
      float4 cv;
      if (k + 3 < K) cv = *(const float4*)&C[(size_t)(d0 + d) * K + k];
      else {
        cv.x = (k + 0 < K) ? C[(size_t)(d0 + d) * K + k + 0] : 0.f;
        cv.y = (k + 1 < K) ? C[(size_t)(d0 + d) * K + k + 1] : 0.f;
        cv.z = (k + 2 < K) ? C[(size_t)(d0 + d) * K + k + 2] : 0.f;
        cv.w = (k + 3 < K) ? C[(size_t)(d0 + d) * K + k + 3] : 0.f;
      }
      *(float4*)&Cs[d][kc] = cv;
    }
    __syncthreads();
#pragma unroll
    for (int d = 0; d < 16; ++d) {
      float4 a0 = *(const float4*)&Xs[d][ty * 8];
      float4 a1 = *(const float4*)&Xs[d][ty * 8 + 4];
      float4 b = *(const float4*)&Cs[d][tx * 4];
      float av[8] = {a0.x, a0.y, a0.z, a0.w, a1.x, a1.y, a1.z, a1.w};
      float bv[4] = {b.x, b.y, b.z, b.w};
#pragma unroll
      for (int i = 0; i < 8; ++i)
#pragma unroll
        for (int j = 0; j < 4; ++j) acc[i][j] = fmaf(av[i], bv[j], acc[i][j]);
    }
    __syncthreads();
  }
  float cnv[4];
#pragma unroll
  for (int j = 0; j < 4; ++j) {
    int k = k0 + tx * 4 + j;
    cnv[j] = (k < K) ? cnorm[k] : 0.f;
  }
#pragma unroll
  for (int i = 0; i < 8; ++i) {
    u64 key = ~0ULL;
#pragma unroll
    for (int j = 0; j < 4; ++j) {
      int k = k0 + tx * 4 + j;
      if (k < K) {
        float score = fmaf(-2.f, acc[i][j], cnv[j]);
        u64 cand = ((u64)fsort(score) << 32) | (unsigned)k;
        key = key < cand ? key : cand;
      }
    }
#pragma unroll
    for (int mk = 8; mk >= 1; mk >>= 1) {
      u64 other = __shfl_xor(key, mk, 16);
      key = key < other ? key : other;
    }
    if (tx == 0) atomicMin(&best[n0 + ty * 8 + i], key);
  }
}

// ---------------- shared output kernel ----------------
__global__ void out_kernel(const u64* __restrict__ best, int* __restrict__ out, int N) {
  int n = blockIdx.x * blockDim.x + threadIdx.x;
  if (n < N) out[n] = (int)(u32)(best[n] & 0xffffffffu);
}

extern "C" void kernel_launch(void* const* d_in, const int* in_sizes, int n_in,
                              void* d_out, int out_size, void* d_ws, size_t ws_size,
                              hipStream_t stream) {
  const float* X = (const float*)d_in[0];  // [N, D]
  const float* C = (const float*)d_in[1];  // [D, K]
  int* out = (int*)d_out;

  // ws layout (MFMA path): best | amin | cnorm | Xb | Cb
  const size_t OFF_BEST = 0;
  const size_t OFF_AMIN = 131072;
  const size_t OFF_CN   = 196608;
  const size_t OFF_XB   = 262144;
  const size_t OFF_CB   = 262144 + (size_t)N_ROWS * DDIM * 2;     // 25427968
  const size_t REQUIRED = OFF_CB + (size_t)KPAD * DDIM * 2;       // 40960000

  if (ws_size >= REQUIRED) {
    u64* best = (u64*)((char*)d_ws + OFF_BEST);
    u32* amin = (u32*)((char*)d_ws + OFF_AMIN);
    float* cnp = (float*)((char*)d_ws + OFF_CN);
    unsigned short* Xb = (unsigned short*)((char*)d_ws + OFF_XB);
    unsigned short* Cb = (unsigned short*)((char*)d_ws + OFF_CB);

    hipLaunchKernelGGL(init2_kernel, dim3(64), dim3(256), 0, stream, best, amin);
    hipLaunchKernelGGL(convx_kernel, dim3(N_ROWS * DDIM / 2048), dim3(256), 0, stream, X, Xb);
    hipLaunchKernelGGL(transc_kernel, dim3(KPAD / 32, DDIM / 32), dim3(256), 0, stream, C, Cb);
    hipLaunchKernelGGL(cnormp_kernel, dim3((KPAD + 255) / 256), dim3(256), 0, stream, C, cnp);
    hipLaunchKernelGGL(assign_mfma, dim3(N_ROWS / 128, KPAD / 128), dim3(256), 0, stream,
                       Xb, Cb, X, C, cnp, amin, best);
    hipLaunchKernelGGL(out_kernel, dim3(64), dim3(256), 0, stream, best, out, N_ROWS);
  } else {
    // fp32 fallback (round-2 passing path)
    u64* best = (u64*)d_ws;
    float* cnorm = (float*)((char*)d_ws + (size_t)N_ROWS * sizeof(u64));
    hipLaunchKernelGGL(init_kernel, dim3(64), dim3(256), 0, stream, best, N_ROWS);
    hipLaunchKernelGGL(cnorm_kernel, dim3((KCOLS + 255) / 256), dim3(256), 0, stream,
                       C, cnorm, DDIM, KCOLS);
    hipLaunchKernelGGL(assign_kernel, dim3((KCOLS + 63) / 64, N_ROWS / 128), dim3(256), 0,
                       stream, X, C, cnorm, best, N_ROWS, DDIM, KCOLS);
    hipLaunchKernelGGL(out_kernel, dim3(64), dim3(256), 0, stream, best, out, N_ROWS);
  }
}

// Round 4
// 749.159 us; speedup vs baseline: 4.3179x; 1.2068x over previous
//
#include <hip/hip_runtime.h>
#include <cfloat>

#define N_ROWS 16384
#define DDIM   768
#define KCOLS  10000
#define KPAD   10112   // 79 * 128

typedef __attribute__((ext_vector_type(4))) float f32x4;
typedef __attribute__((ext_vector_type(8))) short s16x8;
typedef unsigned long long u64;
typedef unsigned int u32;

__device__ __forceinline__ u32 fsort(float f) {
  u32 u = __float_as_uint(f);
  return (u & 0x80000000u) ? ~u : (u | 0x80000000u);
}
__device__ __forceinline__ float funsort(u32 u) {
  u32 b = (u & 0x80000000u) ? (u ^ 0x80000000u) : ~u;
  return __uint_as_float(b);
}
__device__ __forceinline__ unsigned short f2bf(float f) {  // RNE
  u32 b = __float_as_uint(f);
  return (unsigned short)((b + 0x7fffu + ((b >> 16) & 1u)) >> 16);
}
__device__ __forceinline__ float bf2f(unsigned short s) {
  return __uint_as_float(((u32)s) << 16);
}

// ============================ pre-passes ============================

__global__ void init2_kernel(u64* best) {
  int i = blockIdx.x * 256 + threadIdx.x;
  if (i < N_ROWS) best[i] = ~0ULL;
}

// X [N][768] f32 -> Xb [N][768] bf16, chunk-swizzled: store(d) = d ^ ((row&7)<<3)
__global__ void convx_kernel(const float* __restrict__ X, unsigned short* __restrict__ Xb) {
  int i = blockIdx.x * 256 + threadIdx.x;   // output uint4 (8-elem chunk) index
  int row = i / 96;
  int pc  = i % 96;                          // physical chunk within row
  int lc  = pc ^ (row & 7);                  // logical chunk (xor bits 0-2 only)
  const float4* p = (const float4*)(X + (size_t)row * DDIM + lc * 8);
  float4 a = p[0], b = p[1];
  union { unsigned short s[8]; uint4 v; } o;
  o.s[0] = f2bf(a.x); o.s[1] = f2bf(a.y); o.s[2] = f2bf(a.z); o.s[3] = f2bf(a.w);
  o.s[4] = f2bf(b.x); o.s[5] = f2bf(b.y); o.s[6] = f2bf(b.z); o.s[7] = f2bf(b.w);
  *((uint4*)Xb + i) = o.v;
}

// C [768][10000] f32 -> Cb [10112][768] bf16 (swizzled) + Ct [10112][768] f32 (linear)
__global__ void transc_kernel(const float* __restrict__ C, unsigned short* __restrict__ Cb,
                              float* __restrict__ Ct) {
  __shared__ float tile[32][33];
  int t = threadIdx.x, tx = t & 31, ty = t >> 5;
  int kk = blockIdx.x * 32, dd = blockIdx.y * 32;
#pragma unroll
  for (int j = 0; j < 4; ++j) {
    int d = dd + ty + j * 8, k = kk + tx;
    tile[ty + j * 8][tx] = (k < KCOLS) ? C[(size_t)d * KCOLS + k] : 0.f;
  }
  __syncthreads();
#pragma unroll
  for (int j = 0; j < 4; ++j) {
    int k = kk + ty + j * 8, d = dd + tx;
    float v = tile[tx][ty + j * 8];
    Cb[(size_t)k * DDIM + (d ^ ((k & 7) << 3))] = f2bf(v);
    if (Ct) Ct[(size_t)k * DDIM + d] = v;
  }
}

__global__ void cnormp_kernel(const float* __restrict__ C, float* __restrict__ cn) {
  int k = blockIdx.x * 256 + threadIdx.x;
  if (k >= KPAD) return;
  if (k >= KCOLS) { cn[k] = FLT_MAX; return; }
  float s = 0.f;
  for (int d = 0; d < DDIM; ++d) {
    float v = C[(size_t)d * KCOLS + k];
    s = fmaf(v, v, s);
  }
  cn[k] = s;
}

// Seed amin[row] with approx scores of 64 sampled centroids (lane = candidate).
__global__ __launch_bounds__(256) void seed_kernel(
    const unsigned short* __restrict__ Xb, const unsigned short* __restrict__ Cb,
    const float* __restrict__ cn, u32* __restrict__ amin) {
  __shared__ unsigned short xs[4][DDIM];   // logical layout, per-wave slice
  const int wave = threadIdx.x >> 6, lane = threadIdx.x & 63;
  const int row = blockIdx.x * 4 + wave;
  // stage X row: physical chunk p holds logical chunk p ^ (row&7)
#pragma unroll
  for (int p0 = 0; p0 < 2; ++p0) {
    int p = lane + p0 * 64;
    if (p < 96) {
      uint4 v = *((const uint4*)(Xb + (size_t)row * DDIM) + p);
      *((uint4*)(xs[wave] + (p ^ (row & 7)) * 8)) = v;
    }
  }
  // per-lane candidate
  const int k = lane * 158;                // 0..9954
  const int ksw = k & 7;
  const unsigned short* crow = Cb + (size_t)k * DDIM;
  float dot = 0.f;
  for (int p = 0; p < 96; ++p) {
    union { uint4 v; unsigned short s[8]; } cv;
    cv.v = *((const uint4*)crow + p);
    int lc = p ^ ksw;
    const unsigned short* xp = xs[wave] + lc * 8;
#pragma unroll
    for (int j = 0; j < 8; ++j) dot = fmaf(bf2f(xp[j]), bf2f(cv.s[j]), dot);
  }
  float score = fmaf(-2.f, dot, cn[k]);
#pragma unroll
  for (int s = 1; s < 64; s <<= 1) score = fminf(score, __shfl_xor(score, s));
  if (lane == 0) amin[row] = fsort(score);
}

// ============================ fused GEMM + argmin ============================

#define GLOAD_LDS16(gp, lp)                                                     \
  __builtin_amdgcn_global_load_lds((const __attribute__((address_space(1))) void*)(gp), \
                                   (__attribute__((address_space(3))) void*)(lp), 16, 0, 0)

__global__ __launch_bounds__(256) void assign_mfma(
    const unsigned short* __restrict__ Xb, const unsigned short* __restrict__ Cb,
    const float* __restrict__ X32, const float* __restrict__ C32,
    const float* __restrict__ Ct, const float* __restrict__ cn,
    u32* __restrict__ amin, u64* __restrict__ best) {
  __shared__ unsigned short As[128 * 64];   // [row][chunk-swizzled d]
  __shared__ unsigned short Bs[128 * 64];

  const int t = threadIdx.x;
  const int lane = t & 63, wave = t >> 6;
  const int wr = wave >> 1, wc = wave & 1;
  const int n0 = blockIdx.x * 128;
  const int k0 = blockIdx.y * 128;
  const int lr = lane & 15, lg = lane >> 4;
  const int srow = lane >> 3, schunk = lane & 7;
  const int xr = lr & 7;                    // read-side swizzle key (row&7 == lr&7)

  f32x4 acc[4][4];
  f32x4 z = {0.f, 0.f, 0.f, 0.f};
#pragma unroll
  for (int m = 0; m < 4; ++m)
#pragma unroll
    for (int n = 0; n < 4; ++n) acc[m][n] = z;

  const unsigned short* gA[4];
  const unsigned short* gB[4];
  unsigned short* lA[4];
  unsigned short* lB[4];
#pragma unroll
  for (int i = 0; i < 4; ++i) {
    int r = wave * 32 + i * 8 + srow;
    gA[i] = Xb + (size_t)(n0 + r) * DDIM + schunk * 8;
    gB[i] = Cb + (size_t)(k0 + r) * DDIM + schunk * 8;
    lA[i] = As + (wave * 32 + i * 8) * 64;
    lB[i] = Bs + (wave * 32 + i * 8) * 64;
  }

  for (int d0 = 0; d0 < DDIM; d0 += 64) {
#pragma unroll
    for (int i = 0; i < 4; ++i) GLOAD_LDS16(gA[i] + d0, lA[i]);
#pragma unroll
    for (int i = 0; i < 4; ++i) GLOAD_LDS16(gB[i] + d0, lB[i]);
    __syncthreads();
#pragma unroll
    for (int dk = 0; dk < 2; ++dk) {
      s16x8 af[4], bfr[4];
#pragma unroll
      for (int m = 0; m < 4; ++m) {
        int c = (dk * 4 + lg) ^ xr;         // physical chunk
        af[m] = *(const s16x8*)(As + (wr * 64 + m * 16 + lr) * 64 + c * 8);
      }
#pragma unroll
      for (int n = 0; n < 4; ++n) {
        int c = (dk * 4 + lg) ^ xr;
        bfr[n] = *(const s16x8*)(Bs + (wc * 64 + n * 16 + lr) * 64 + c * 8);
      }
#pragma unroll
      for (int m = 0; m < 4; ++m)
#pragma unroll
        for (int n = 0; n < 4; ++n)
          acc[m][n] = __builtin_amdgcn_mfma_f32_16x16x32_bf16(af[m], bfr[n], acc[m][n], 0, 0, 0);
    }
    __syncthreads();
  }

  // ---------------- epilogue: approx min + exact rescore ----------------
  float cnv[4];
#pragma unroll
  for (int n = 0; n < 4; ++n) cnv[n] = cn[k0 + wc * 64 + n * 16 + lr];

#pragma unroll
  for (int m = 0; m < 4; ++m) {
    float sc[4][4];  // [n][e]
#pragma unroll
    for (int n = 0; n < 4; ++n)
#pragma unroll
      for (int e = 0; e < 4; ++e) sc[n][e] = fmaf(-2.f, acc[m][n][e], cnv[n]);

    float th[4];
#pragma unroll
    for (int e = 0; e < 4; ++e) {
      float v = fminf(fminf(sc[0][e], sc[1][e]), fminf(sc[2][e], sc[3][e]));
      u32 key = fsort(v);
#pragma unroll
      for (int s = 1; s < 16; s <<= 1) {
        u32 o = __shfl_xor(key, s);
        key = key < o ? key : o;
      }
      int row = n0 + wr * 64 + m * 16 + lg * 4 + e;
      u32 mr = key;
      if (lr == 0) {
        u32 old = atomicMin(&amin[row], key);
        mr = old < key ? old : key;
      }
      mr = __shfl(mr, lane & 48);
      th[e] = funsort(mr) + 1.5f;   // margin = 7 sigma of bf16-approx error diff
    }

#pragma unroll
    for (int n = 0; n < 4; ++n) {
#pragma unroll
      for (int e = 0; e < 4; ++e) {
        int kq = k0 + wc * 64 + n * 16 + lr;
        bool cand = (kq < KCOLS) && (sc[n][e] <= th[e]);
        u64 mask = __ballot(cand);
        while (mask) {
          int src = (int)__builtin_ctzll(mask);
          mask &= mask - 1;
          int srowg = n0 + wr * 64 + m * 16 + ((src >> 4) & 3) * 4 + e;
          int skg = k0 + wc * 64 + n * 16 + (src & 15);
          // exact fp32 dot, 64-lane parallel
          float part = 0.f;
          const float* xp = X32 + (size_t)srowg * DDIM + lane;
          if (Ct) {
            const float* cp = Ct + (size_t)skg * DDIM + lane;   // coalesced
#pragma unroll
            for (int i = 0; i < 12; ++i)
              part = fmaf(xp[i * 64], cp[i * 64], part);
          } else {
            const float* cp = C32 + (size_t)lane * KCOLS + skg; // scattered fallback
#pragma unroll
            for (int i = 0; i < 12; ++i)
              part = fmaf(xp[i * 64], cp[(size_t)i * 64 * KCOLS], part);
          }
#pragma unroll
          for (int s = 1; s < 64; s <<= 1) part += __shfl_xor(part, s);
          if (lane == 0) {
            float ex = fmaf(-2.f, part, cn[skg]);
            atomicMin(&best[srowg], ((u64)fsort(ex) << 32) | (u32)skg);
          }
        }
      }
    }
  }
}

// ============================ fp32 fallback path ============================

__global__ void cnorm_kernel(const float* __restrict__ C, float* __restrict__ cnorm,
                             int D, int K) {
  int k = blockIdx.x * blockDim.x + threadIdx.x;
  if (k >= K) return;
  float s = 0.f;
  for (int d = 0; d < D; ++d) {
    float v = C[(size_t)d * K + k];
    s = fmaf(v, v, s);
  }
  cnorm[k] = s;
}

__global__ void init_kernel(u64* best, int N) {
  int n = blockIdx.x * blockDim.x + threadIdx.x;
  if (n < N) best[n] = ~0ULL;
}

__global__ __launch_bounds__(256) void assign_kernel(
    const float* __restrict__ X, const float* __restrict__ C,
    const float* __restrict__ cnorm, u64* __restrict__ best,
    int N, int D, int K) {
  __shared__ float Xs[16][128];
  __shared__ float Cs[16][64];
  const int t = threadIdx.x;
  const int tx = t & 15, ty = t >> 4;
  const int k0 = blockIdx.x * 64;
  const int n0 = blockIdx.y * 128;
  float acc[8][4];
#pragma unroll
  for (int i = 0; i < 8; ++i)
#pragma unroll
    for (int j = 0; j < 4; ++j) acc[i][j] = 0.f;
  for (int d0 = 0; d0 < D; d0 += 16) {
#pragma unroll
    for (int v = 0; v < 2; ++v) {
      int f4 = t + v * 256;
      int row = f4 >> 2;
      int dc = (f4 & 3) * 4;
      const float4 xv = *(const float4*)&X[(size_t)(n0 + row) * D + d0 + dc];
      Xs[dc + 0][row] = xv.x; Xs[dc + 1][row] = xv.y;
      Xs[dc + 2][row] = xv.z; Xs[dc + 3][row] = xv.w;
    }
    {
      int d = t >> 4, kc = (t & 15) * 4, k = k0 + kc;
      float4 cv;
      if (k + 3 < K) cv = *(const float4*)&C[(size_t)(d0 + d) * K + k];
      else {
        cv.x = (k + 0 < K) ? C[(size_t)(d0 + d) * K + k + 0] : 0.f;
        cv.y = (k + 1 < K) ? C[(size_t)(d0 + d) * K + k + 1] : 0.f;
        cv.z = (k + 2 < K) ? C[(size_t)(d0 + d) * K + k + 2] : 0.f;
        cv.w = (k + 3 < K) ? C[(size_t)(d0 + d) * K + k + 3] : 0.f;
      }
      *(float4*)&Cs[d][kc] = cv;
    }
    __syncthreads();
#pragma unroll
    for (int d = 0; d < 16; ++d) {
      float4 a0 = *(const float4*)&Xs[d][ty * 8];
      float4 a1 = *(const float4*)&Xs[d][ty * 8 + 4];
      float4 b = *(const float4*)&Cs[d][tx * 4];
      float av[8] = {a0.x, a0.y, a0.z, a0.w, a1.x, a1.y, a1.z, a1.w};
      float bv[4] = {b.x, b.y, b.z, b.w};
#pragma unroll
      for (int i = 0; i < 8; ++i)
#pragma unroll
        for (int j = 0; j < 4; ++j) acc[i][j] = fmaf(av[i], bv[j], acc[i][j]);
    }
    __syncthreads();
  }
  float cnv[4];
#pragma unroll
  for (int j = 0; j < 4; ++j) {
    int k = k0 + tx * 4 + j;
    cnv[j] = (k < K) ? cnorm[k] : 0.f;
  }
#pragma unroll
  for (int i = 0; i < 8; ++i) {
    u64 key = ~0ULL;
#pragma unroll
    for (int j = 0; j < 4; ++j) {
      int k = k0 + tx * 4 + j;
      if (k < K) {
        float score = fmaf(-2.f, acc[i][j], cnv[j]);
        u64 cand = ((u64)fsort(score) << 32) | (unsigned)k;
        key = key < cand ? key : cand;
      }
    }
#pragma unroll
    for (int mk = 8; mk >= 1; mk >>= 1) {
      u64 other = __shfl_xor(key, mk, 16);
      key = key < other ? key : other;
    }
    if (tx == 0) atomicMin(&best[n0 + ty * 8 + i], key);
  }
}

// ---------------- shared output kernel ----------------
__global__ void out_kernel(const u64* __restrict__ best, int* __restrict__ out, int N) {
  int n = blockIdx.x * blockDim.x + threadIdx.x;
  if (n < N) out[n] = (int)(u32)(best[n] & 0xffffffffu);
}

extern "C" void kernel_launch(void* const* d_in, const int* in_sizes, int n_in,
                              void* d_out, int out_size, void* d_ws, size_t ws_size,
                              hipStream_t stream) {
  const float* X = (const float*)d_in[0];  // [N, D]
  const float* C = (const float*)d_in[1];  // [D, K]
  int* out = (int*)d_out;

  // ws layout: best | amin | cnorm | Xb | Cb | Ct
  const size_t OFF_BEST = 0;
  const size_t OFF_AMIN = 131072;
  const size_t OFF_CN   = 196608;
  const size_t OFF_XB   = 262144;
  const size_t OFF_CB   = OFF_XB + (size_t)N_ROWS * DDIM * 2;     // 25427968
  const size_t OFF_CT   = OFF_CB + (size_t)KPAD * DDIM * 2;       // 40960000
  const size_t REQ_B    = OFF_CT;                                 // no Ct
  const size_t REQ_A    = OFF_CT + (size_t)KPAD * DDIM * 4;       // 72024064

  if (ws_size >= REQ_B) {
    u64* best = (u64*)((char*)d_ws + OFF_BEST);
    u32* amin = (u32*)((char*)d_ws + OFF_AMIN);
    float* cnp = (float*)((char*)d_ws + OFF_CN);
    unsigned short* Xb = (unsigned short*)((char*)d_ws + OFF_XB);
    unsigned short* Cb = (unsigned short*)((char*)d_ws + OFF_CB);
    float* Ct = (ws_size >= REQ_A) ? (float*)((char*)d_ws + OFF_CT) : nullptr;

    hipLaunchKernelGGL(init2_kernel, dim3(64), dim3(256), 0, stream, best);
    hipLaunchKernelGGL(convx_kernel, dim3(N_ROWS * 96 / 256), dim3(256), 0, stream, X, Xb);
    hipLaunchKernelGGL(transc_kernel, dim3(KPAD / 32, DDIM / 32), dim3(256), 0, stream, C, Cb, Ct);
    hipLaunchKernelGGL(cnormp_kernel, dim3((KPAD + 255) / 256), dim3(256), 0, stream, C, cnp);
    hipLaunchKernelGGL(seed_kernel, dim3(N_ROWS / 4), dim3(256), 0, stream, Xb, Cb, cnp, amin);
    hipLaunchKernelGGL(assign_mfma, dim3(N_ROWS / 128, KPAD / 128), dim3(256), 0, stream,
                       Xb, Cb, X, C, Ct, cnp, amin, best);
    hipLaunchKernelGGL(out_kernel, dim3(64), dim3(256), 0, stream, best, out, N_ROWS);
  } else {
    // fp32 fallback (round-2 passing path)
    u64* best = (u64*)d_ws;
    float* cnorm = (float*)((char*)d_ws + (size_t)N_ROWS * sizeof(u64));
    hipLaunchKernelGGL(init_kernel, dim3(64), dim3(256), 0, stream, best, N_ROWS);
    hipLaunchKernelGGL(cnorm_kernel, dim3((KCOLS + 255) / 256), dim3(256), 0, stream,
                       C, cnorm, DDIM, KCOLS);
    hipLaunchKernelGGL(assign_kernel, dim3((KCOLS + 63) / 64, N_ROWS / 128), dim3(256), 0,
                       stream, X, C, cnorm, best, N_ROWS, DDIM, KCOLS);
    hipLaunchKernelGGL(out_kernel, dim3(64), dim3(256), 0, stream, best, out, N_ROWS);
  }
}

// Round 5
// 628.159 us; speedup vs baseline: 5.1497x; 1.1926x over previous
//
#include <hip/hip_runtime.h>
#include <cfloat>

#define N_ROWS 16384
#define DDIM   768
#define KCOLS  10000
#define KPAD   10112   // 79 * 128

typedef __attribute__((ext_vector_type(4))) float f32x4;
typedef __attribute__((ext_vector_type(8))) short s16x8;
typedef unsigned long long u64;
typedef unsigned int u32;

__device__ __forceinline__ u32 fsort(float f) {
  u32 u = __float_as_uint(f);
  return (u & 0x80000000u) ? ~u : (u | 0x80000000u);
}
__device__ __forceinline__ float funsort(u32 u) {
  u32 b = (u & 0x80000000u) ? (u ^ 0x80000000u) : ~u;
  return __uint_as_float(b);
}
__device__ __forceinline__ unsigned short f2bf(float f) {  // RNE
  u32 b = __float_as_uint(f);
  return (unsigned short)((b + 0x7fffu + ((b >> 16) & 1u)) >> 16);
}
__device__ __forceinline__ float bf2f(unsigned short s) {
  return __uint_as_float(((u32)s) << 16);
}

// ============================ pre-passes ============================

// X [N][768] f32 -> Xb [N][768] bf16, chunk-swizzled: store(d) = d ^ ((row&7)<<3)
// Also initializes best[] (folded launch).
__global__ void convx_kernel(const float* __restrict__ X, unsigned short* __restrict__ Xb,
                             u64* __restrict__ best) {
  int i = blockIdx.x * 256 + threadIdx.x;   // output uint4 (8-elem chunk) index
  if (i < N_ROWS) best[i] = ~0ULL;
  int row = i / 96;
  int pc  = i % 96;                          // physical chunk within row
  int lc  = pc ^ (row & 7);                  // logical chunk (xor bits 0-2 only)
  const float4* p = (const float4*)(X + (size_t)row * DDIM + lc * 8);
  float4 a = p[0], b = p[1];
  union { unsigned short s[8]; uint4 v; } o;
  o.s[0] = f2bf(a.x); o.s[1] = f2bf(a.y); o.s[2] = f2bf(a.z); o.s[3] = f2bf(a.w);
  o.s[4] = f2bf(b.x); o.s[5] = f2bf(b.y); o.s[6] = f2bf(b.z); o.s[7] = f2bf(b.w);
  *((uint4*)Xb + i) = o.v;
}

// C [768][10000] f32 -> Cb [10112][768] bf16 (swizzled) + Ct [10112][768] f32 (linear)
__global__ void transc_kernel(const float* __restrict__ C, unsigned short* __restrict__ Cb,
                              float* __restrict__ Ct) {
  __shared__ float tile[32][33];
  int t = threadIdx.x, tx = t & 31, ty = t >> 5;
  int kk = blockIdx.x * 32, dd = blockIdx.y * 32;
#pragma unroll
  for (int j = 0; j < 4; ++j) {
    int d = dd + ty + j * 8, k = kk + tx;
    tile[ty + j * 8][tx] = (k < KCOLS) ? C[(size_t)d * KCOLS + k] : 0.f;
  }
  __syncthreads();
#pragma unroll
  for (int j = 0; j < 4; ++j) {
    int k = kk + ty + j * 8, d = dd + tx;
    float v = tile[tx][ty + j * 8];
    Cb[(size_t)k * DDIM + (d ^ ((k & 7) << 3))] = f2bf(v);
    if (Ct) Ct[(size_t)k * DDIM + d] = v;
  }
}

// cnorm, 2D-parallel, deterministic fixed-order reduction. grid = KPAD/64.
__global__ __launch_bounds__(256) void cnorm2_kernel(const float* __restrict__ C,
                                                     float* __restrict__ cn) {
  __shared__ float part[4][64];
  const int tx = threadIdx.x & 63, ty = threadIdx.x >> 6;
  const int k = blockIdx.x * 64 + tx;
  float s = 0.f;
  if (k < KCOLS) {
    const float* p = C + (size_t)(ty * 192) * KCOLS + k;
    for (int d = 0; d < 192; ++d) {
      float v = p[(size_t)d * KCOLS];
      s = fmaf(v, v, s);
    }
  }
  part[ty][tx] = s;
  __syncthreads();
  if (ty == 0)
    cn[k] = (k < KCOLS) ? ((part[0][tx] + part[1][tx]) + (part[2][tx] + part[3][tx]))
                        : FLT_MAX;
}

// Seed amin[row]: approx scores of 64 sampled centroids (lane = candidate).
// X row staged as f32 (exact); centroids from swizzled bf16 Cb.
__global__ __launch_bounds__(256) void seed_kernel(
    const float* __restrict__ X32, const unsigned short* __restrict__ Cb,
    const float* __restrict__ cn, u32* __restrict__ amin) {
  __shared__ float xs[4][DDIM];
  const int wave = threadIdx.x >> 6, lane = threadIdx.x & 63;
  const int row = blockIdx.x * 4 + wave;
  const float4* xr = (const float4*)(X32 + (size_t)row * DDIM);
#pragma unroll
  for (int p0 = 0; p0 < 3; ++p0)
    ((float4*)xs[wave])[lane + p0 * 64] = xr[lane + p0 * 64];
  const int k = lane * 158;                 // 0..9954
  const int ksw = k & 7;
  const uint4* crow = (const uint4*)(Cb + (size_t)k * DDIM);
  float dot = 0.f;
  for (int p = 0; p < 96; ++p) {
    union { uint4 v; unsigned short s[8]; } cv;
    cv.v = crow[p];
    const float* xp = xs[wave] + ((p ^ ksw) * 8);
#pragma unroll
    for (int j = 0; j < 8; ++j) dot = fmaf(xp[j], bf2f(cv.s[j]), dot);
  }
  float score = fmaf(-2.f, dot, cn[k]);
#pragma unroll
  for (int s = 1; s < 64; s <<= 1) score = fminf(score, __shfl_xor(score, s));
  if (lane == 0) amin[row] = fsort(score);
}

// ============================ fused GEMM + argmin ============================

#define GLOAD_LDS16(gp, lp)                                                     \
  __builtin_amdgcn_global_load_lds((const __attribute__((address_space(1))) void*)(gp), \
                                   (__attribute__((address_space(3))) void*)(lp), 16, 0, 0)

__global__ __launch_bounds__(256, 3) void assign_mfma(
    const unsigned short* __restrict__ Xb, const unsigned short* __restrict__ Cb,
    const float* __restrict__ X32, const float* __restrict__ C32,
    const float* __restrict__ Ct, const float* __restrict__ cn,
    u32* __restrict__ amin, u64* __restrict__ best) {
  __shared__ unsigned short As[128 * 64];   // [row][chunk-swizzled d]
  __shared__ unsigned short Bs[128 * 64];

  const int t = threadIdx.x;
  const int lane = t & 63, wave = t >> 6;
  const int wr = wave >> 1, wc = wave & 1;
  const int n0 = blockIdx.x * 128;
  const int k0 = blockIdx.y * 128;
  const int lr = lane & 15, lg = lane >> 4;
  const int srow = lane >> 3, schunk = lane & 7;
  const int xr = lr & 7;                    // read-side swizzle key (row&7 == lr&7)

  f32x4 acc[4][4];
  f32x4 z = {0.f, 0.f, 0.f, 0.f};
#pragma unroll
  for (int m = 0; m < 4; ++m)
#pragma unroll
    for (int n = 0; n < 4; ++n) acc[m][n] = z;

  // rolling base pointers (rematerialize per-iteration offsets -> low VGPR)
  const unsigned short* gA = Xb + (size_t)(n0 + wave * 32 + srow) * DDIM + schunk * 8;
  const unsigned short* gB = Cb + (size_t)(k0 + wave * 32 + srow) * DDIM + schunk * 8;

  for (int it = 0; it < DDIM / 64; ++it) {
#pragma unroll
    for (int i = 0; i < 4; ++i) {
      GLOAD_LDS16(gA + (size_t)i * 8 * DDIM, As + (wave * 32 + i * 8) * 64);
      GLOAD_LDS16(gB + (size_t)i * 8 * DDIM, Bs + (wave * 32 + i * 8) * 64);
    }
    gA += 64; gB += 64;
    __syncthreads();
#pragma unroll
    for (int dk = 0; dk < 2; ++dk) {
      s16x8 af[4], bfr[4];
      const int c = (dk * 4 + lg) ^ xr;     // physical chunk
#pragma unroll
      for (int m = 0; m < 4; ++m)
        af[m] = *(const s16x8*)(As + (wr * 64 + m * 16 + lr) * 64 + c * 8);
#pragma unroll
      for (int n = 0; n < 4; ++n)
        bfr[n] = *(const s16x8*)(Bs + (wc * 64 + n * 16 + lr) * 64 + c * 8);
#pragma unroll
      for (int m = 0; m < 4; ++m)
#pragma unroll
        for (int n = 0; n < 4; ++n)
          acc[m][n] = __builtin_amdgcn_mfma_f32_16x16x32_bf16(af[m], bfr[n], acc[m][n], 0, 0, 0);
    }
    __syncthreads();
  }

  // ---------------- epilogue: approx min + exact rescore ----------------
  float cnv[4];
#pragma unroll
  for (int n = 0; n < 4; ++n) cnv[n] = cn[k0 + wc * 64 + n * 16 + lr];

#pragma unroll
  for (int m = 0; m < 4; ++m) {
    float sc[4][4];  // [n][e]
#pragma unroll
    for (int n = 0; n < 4; ++n)
#pragma unroll
      for (int e = 0; e < 4; ++e) sc[n][e] = fmaf(-2.f, acc[m][n][e], cnv[n]);

    float th[4];
#pragma unroll
    for (int e = 0; e < 4; ++e) {
      float v = fminf(fminf(sc[0][e], sc[1][e]), fminf(sc[2][e], sc[3][e]));
      u32 key = fsort(v);
#pragma unroll
      for (int s = 1; s < 16; s <<= 1) {
        u32 o = __shfl_xor(key, s);
        key = key < o ? key : o;
      }
      int row = n0 + wr * 64 + m * 16 + lg * 4 + e;
      u32 mr = key;
      if (lr == 0) {
        u32 old = atomicMin(&amin[row], key);
        mr = old < key ? old : key;
      }
      mr = __shfl(mr, lane & 48);
      th[e] = funsort(mr) + 1.5f;   // margin ~ 7 sigma of bf16-approx error diff
    }

#pragma unroll
    for (int n = 0; n < 4; ++n) {
#pragma unroll
      for (int e = 0; e < 4; ++e) {
        int kq = k0 + wc * 64 + n * 16 + lr;
        bool cand = (kq < KCOLS) && (sc[n][e] <= th[e]);
        u64 mask = __ballot(cand);
        while (mask) {
          int src = (int)__builtin_ctzll(mask);
          mask &= mask - 1;
          int srowg = n0 + wr * 64 + m * 16 + ((src >> 4) & 3) * 4 + e;
          int skg = k0 + wc * 64 + n * 16 + (src & 15);
          // exact fp32 dot, 64-lane parallel
          float part = 0.f;
          const float* xp = X32 + (size_t)srowg * DDIM + lane;
          if (Ct) {
            const float* cp = Ct + (size_t)skg * DDIM + lane;   // coalesced
#pragma unroll
            for (int i = 0; i < 12; ++i)
              part = fmaf(xp[i * 64], cp[i * 64], part);
          } else {
            const float* cp = C32 + (size_t)lane * KCOLS + skg; // scattered fallback
#pragma unroll
            for (int i = 0; i < 12; ++i)
              part = fmaf(xp[i * 64], cp[(size_t)i * 64 * KCOLS], part);
          }
#pragma unroll
          for (int s = 1; s < 64; s <<= 1) part += __shfl_xor(part, s);
          if (lane == 0) {
            float ex = fmaf(-2.f, part, cn[skg]);
            atomicMin(&best[srowg], ((u64)fsort(ex) << 32) | (u32)skg);
          }
        }
      }
    }
  }
}

// ============================ fp32 fallback path ============================

__global__ void cnorm_kernel(const float* __restrict__ C, float* __restrict__ cnorm,
                             int D, int K) {
  int k = blockIdx.x * blockDim.x + threadIdx.x;
  if (k >= K) return;
  float s = 0.f;
  for (int d = 0; d < D; ++d) {
    float v = C[(size_t)d * K + k];
    s = fmaf(v, v, s);
  }
  cnorm[k] = s;
}

__global__ void init_kernel(u64* best, int N) {
  int n = blockIdx.x * blockDim.x + threadIdx.x;
  if (n < N) best[n] = ~0ULL;
}

__global__ __launch_bounds__(256) void assign_kernel(
    const float* __restrict__ X, const float* __restrict__ C,
    const float* __restrict__ cnorm, u64* __restrict__ best,
    int N, int D, int K) {
  __shared__ float Xs[16][128];
  __shared__ float Cs[16][64];
  const int t = threadIdx.x;
  const int tx = t & 15, ty = t >> 4;
  const int k0 = blockIdx.x * 64;
  const int n0 = blockIdx.y * 128;
  float acc[8][4];
#pragma unroll
  for (int i = 0; i < 8; ++i)
#pragma unroll
    for (int j = 0; j < 4; ++j) acc[i][j] = 0.f;
  for (int d0 = 0; d0 < D; d0 += 16) {
#pragma unroll
    for (int v = 0; v < 2; ++v) {
      int f4 = t + v * 256;
      int row = f4 >> 2;
      int dc = (f4 & 3) * 4;
      const float4 xv = *(const float4*)&X[(size_t)(n0 + row) * D + d0 + dc];
      Xs[dc + 0][row] = xv.x; Xs[dc + 1][row] = xv.y;
      Xs[dc + 2][row] = xv.z; Xs[dc + 3][row] = xv.w;
    }
    {
      int d = t >> 4, kc = (t & 15) * 4, k = k0 + kc;
      float4 cv;
      if (k + 3 < K) cv = *(const float4*)&C[(size_t)(d0 + d) * K + k];
      else {
        cv.x = (k + 0 < K) ? C[(size_t)(d0 + d) * K + k + 0] : 0.f;
        cv.y = (k + 1 < K) ? C[(size_t)(d0 + d) * K + k + 1] : 0.f;
        cv.z = (k + 2 < K) ? C[(size_t)(d0 + d) * K + k + 2] : 0.f;
        cv.w = (k + 3 < K) ? C[(size_t)(d0 + d) * K + k + 3] : 0.f;
      }
      *(float4*)&Cs[d][kc] = cv;
    }
    __syncthreads();
#pragma unroll
    for (int d = 0; d < 16; ++d) {
      float4 a0 = *(const float4*)&Xs[d][ty * 8];
      float4 a1 = *(const float4*)&Xs[d][ty * 8 + 4];
      float4 b = *(const float4*)&Cs[d][tx * 4];
      float av[8] = {a0.x, a0.y, a0.z, a0.w, a1.x, a1.y, a1.z, a1.w};
      float bv[4] = {b.x, b.y, b.z, b.w};
#pragma unroll
      for (int i = 0; i < 8; ++i)
#pragma unroll
        for (int j = 0; j < 4; ++j) acc[i][j] = fmaf(av[i], bv[j], acc[i][j]);
    }
    __syncthreads();
  }
  float cnv[4];
#pragma unroll
  for (int j = 0; j < 4; ++j) {
    int k = k0 + tx * 4 + j;
    cnv[j] = (k < K) ? cnorm[k] : 0.f;
  }
#pragma unroll
  for (int i = 0; i < 8; ++i) {
    u64 key = ~0ULL;
#pragma unroll
    for (int j = 0; j < 4; ++j) {
      int k = k0 + tx * 4 + j;
      if (k < K) {
        float score = fmaf(-2.f, acc[i][j], cnv[j]);
        u64 cand = ((u64)fsort(score) << 32) | (unsigned)k;
        key = key < cand ? key : cand;
      }
    }
#pragma unroll
    for (int mk = 8; mk >= 1; mk >>= 1) {
      u64 other = __shfl_xor(key, mk, 16);
      key = key < other ? key : other;
    }
    if (tx == 0) atomicMin(&best[n0 + ty * 8 + i], key);
  }
}

// ---------------- shared output kernel ----------------
__global__ void out_kernel(const u64* __restrict__ best, int* __restrict__ out, int N) {
  int n = blockIdx.x * blockDim.x + threadIdx.x;
  if (n < N) out[n] = (int)(u32)(best[n] & 0xffffffffu);
}

extern "C" void kernel_launch(void* const* d_in, const int* in_sizes, int n_in,
                              void* d_out, int out_size, void* d_ws, size_t ws_size,
                              hipStream_t stream) {
  const float* X = (const float*)d_in[0];  // [N, D]
  const float* C = (const float*)d_in[1];  // [D, K]
  int* out = (int*)d_out;

  // ws layout: best | amin | cnorm | Xb | Cb | Ct
  const size_t OFF_BEST = 0;
  const size_t OFF_AMIN = 131072;
  const size_t OFF_CN   = 196608;
  const size_t OFF_XB   = 262144;
  const size_t OFF_CB   = OFF_XB + (size_t)N_ROWS * DDIM * 2;     // 25427968
  const size_t OFF_CT   = OFF_CB + (size_t)KPAD * DDIM * 2;       // 40960000
  const size_t REQ_B    = OFF_CT;                                 // no Ct
  const size_t REQ_A    = OFF_CT + (size_t)KPAD * DDIM * 4;       // 72024064

  if (ws_size >= REQ_B) {
    u64* best = (u64*)((char*)d_ws + OFF_BEST);
    u32* amin = (u32*)((char*)d_ws + OFF_AMIN);
    float* cnp = (float*)((char*)d_ws + OFF_CN);
    unsigned short* Xb = (unsigned short*)((char*)d_ws + OFF_XB);
    unsigned short* Cb = (unsigned short*)((char*)d_ws + OFF_CB);
    float* Ct = (ws_size >= REQ_A) ? (float*)((char*)d_ws + OFF_CT) : nullptr;

    hipLaunchKernelGGL(convx_kernel, dim3(N_ROWS * 96 / 256), dim3(256), 0, stream, X, Xb, best);
    hipLaunchKernelGGL(transc_kernel, dim3(KPAD / 32, DDIM / 32), dim3(256), 0, stream, C, Cb, Ct);
    hipLaunchKernelGGL(cnorm2_kernel, dim3(KPAD / 64), dim3(256), 0, stream, C, cnp);
    hipLaunchKernelGGL(seed_kernel, dim3(N_ROWS / 4), dim3(256), 0, stream, X, Cb, cnp, amin);
    hipLaunchKernelGGL(assign_mfma, dim3(N_ROWS / 128, KPAD / 128), dim3(256), 0, stream,
                       Xb, Cb, X, C, Ct, cnp, amin, best);
    hipLaunchKernelGGL(out_kernel, dim3(64), dim3(256), 0, stream, best, out, N_ROWS);
  } else {
    // fp32 fallback (round-2 passing path)
    u64* best = (u64*)d_ws;
    float* cnorm = (float*)((char*)d_ws + (size_t)N_ROWS * sizeof(u64));
    hipLaunchKernelGGL(init_kernel, dim3(64), dim3(256), 0, stream, best, N_ROWS);
    hipLaunchKernelGGL(cnorm_kernel, dim3((KCOLS + 255) / 256), dim3(256), 0, stream,
                       C, cnorm, DDIM, KCOLS);
    hipLaunchKernelGGL(assign_kernel, dim3((KCOLS + 63) / 64, N_ROWS / 128), dim3(256), 0,
                       stream, X, C, cnorm, best, N_ROWS, DDIM, KCOLS);
    hipLaunchKernelGGL(out_kernel, dim3(64), dim3(256), 0, stream, best, out, N_ROWS);
  }
}